// Round 1
// baseline (3232.719 us; speedup 1.0000x reference)
//
#include <hip/hip_runtime.h>
#include <math.h>

#ifndef M_PI
#define M_PI 3.14159265358979323846
#endif

#define NN   64
#define CC   256
#define SS   30
#define HWW  176
#define TOPK 10

// K0: build doubled filter table hh[0..511], hh[i] = h[i & 255], in fp64.
// h[d] = (1/256) [ G(0) + (-1)^d G(128) + 2 * sum_{m=1}^{127} G(m) cos(2 pi d m / 256) ]
// with G(m) = exp(-0.5 * (m/32)^2)  (Gaussian low-pass, sigma=0.25 of Nyquist).
__global__ void build_filter_kernel(float* __restrict__ hh) {
    const int d = threadIdx.x;           // 0..255
    const double theta = (2.0 * M_PI * (double)d) / 256.0;
    const double ct = cos(theta);
    double cm_prev = 1.0;                // cos(0*theta)
    double cm = ct;                      // cos(1*theta)
    double acc = 0.0;
    for (int m = 1; m <= 127; ++m) {
        const double mm = (double)m / 32.0;
        const double G = exp(-0.5 * mm * mm);
        acc += G * cm;                   // G(m) * cos(m*theta)
        const double cn = 2.0 * ct * cm - cm_prev;  // Chebyshev recurrence
        cm_prev = cm;
        cm = cn;
    }
    const double G128 = exp(-8.0);
    double h = 1.0 + 2.0 * acc + ((d & 1) ? -G128 : G128);
    h /= 256.0;
    hh[d]       = (float)h;
    hh[d + 256] = (float)h;
}

// Main fused kernel: one wave (64 threads) per (n, hw) pair.
// Lane l owns channels c = l + 64*j, j=0..3.  x rows x[k][s] are wave-uniform
// -> scalar loads; h taps read from doubled LDS table (stride-1, conflict-free).
__global__ __launch_bounds__(64, 3)
void last_pool_kernel(const float* __restrict__ seqs,
                      const float* __restrict__ logit_p,
                      const float* __restrict__ hh_g,
                      float* __restrict__ out) {
    __shared__ float hh[512];
    const int lane = threadIdx.x;        // 0..63
    const int hw = blockIdx.x % HWW;
    const int n  = blockIdx.x / HWW;

    for (int i = lane; i < 512; i += 64) hh[i] = hh_g[i];
    __syncthreads();

    float acc[4][SS];
    #pragma unroll
    for (int j = 0; j < 4; ++j)
        #pragma unroll
        for (int s = 0; s < SS; ++s) acc[j][s] = 0.0f;

    const size_t row_stride = (size_t)SS * HWW;           // 5280 floats per (n,c)
    const float* __restrict__ xbase = seqs + (size_t)n * CC * row_stride + hw;

    // Circular conv along c:  low[c] = sum_k h[(c-k) mod 256] * x[k]
    for (int k = 0; k < CC; ++k) {
        const float* __restrict__ xrow = xbase + (size_t)k * row_stride;  // uniform
        const int hbase = lane + 256 - k;                  // in [1, 511]
        const float h0 = hh[hbase];
        const float h1 = hh[hbase + 64];
        const float h2 = hh[hbase + 128];
        const float h3 = hh[hbase + 192];
        #pragma unroll
        for (int s = 0; s < SS; ++s) {
            const float xv = xrow[(size_t)s * HWW];        // wave-uniform -> s_load
            acc[0][s] = fmaf(xv, h0, acc[0][s]);
            acc[1][s] = fmaf(xv, h1, acc[1][s]);
            acc[2][s] = fmaf(xv, h2, acc[2][s]);
            acc[3][s] = fmaf(xv, h3, acc[3][s]);
        }
    }

    const float logit = logit_p[0];
    const float alpha = 1.0f / (1.0f + expf(-logit));
    const float beta  = 1.0f - alpha;

    // Epilogue: score = |low| / (|low - x| + eps); top-10 over s; mean + max fuse.
    #pragma unroll
    for (int j = 0; j < 4; ++j) {
        const int c = lane + 64 * j;
        const float* __restrict__ xr =
            seqs + ((size_t)(n * CC + c)) * row_stride + hw;
        float mmax = -INFINITY;
        #pragma unroll
        for (int s = 0; s < SS; ++s) {
            const float xv = xr[(size_t)s * HWW];          // per-lane scattered load
            const float lo = acc[j][s];
            acc[j][s] = fabsf(lo) / (fabsf(lo - xv) + 1e-6f);  // overwrite with score
            mmax = fmaxf(mmax, xv);
        }
        // top-10 (lowest index wins ties, matching lax.top_k), via bitmask —
        // no dynamic register-array indexing.
        unsigned taken = 0u;
        float sum = 0.0f;
        #pragma unroll 1
        for (int t = 0; t < TOPK; ++t) {
            float best = -1.0f;                            // scores are >= 0
            int bi = 0;
            #pragma unroll
            for (int s = 0; s < SS; ++s) {
                const float v = acc[j][s];
                const bool ok = (((taken >> s) & 1u) == 0u) && (v > best);
                best = ok ? v : best;
                bi   = ok ? s : bi;
            }
            taken |= (1u << bi);
            sum += xr[(size_t)bi * HWW];                   // gather selected frame
        }
        out[((size_t)(n * CC + c)) * HWW + hw] =
            alpha * (sum / 10.0f) + beta * mmax;
    }
}

extern "C" void kernel_launch(void* const* d_in, const int* in_sizes, int n_in,
                              void* d_out, int out_size, void* d_ws, size_t ws_size,
                              hipStream_t stream) {
    const float* seqs   = (const float*)d_in[0];
    const float* logitp = (const float*)d_in[1];
    float* hh  = (float*)d_ws;   // 512 floats = 2 KB of scratch
    float* outp = (float*)d_out;

    hipLaunchKernelGGL(build_filter_kernel, dim3(1), dim3(256), 0, stream, hh);
    hipLaunchKernelGGL(last_pool_kernel, dim3(NN * HWW), dim3(64), 0, stream,
                       seqs, logitp, hh, outp);
}

// Round 4
// 2043.849 us; speedup vs baseline: 1.5817x; 1.5817x over previous
//
#include <hip/hip_runtime.h>
#include <math.h>

#ifndef M_PI
#define M_PI 3.14159265358979323846
#endif

#define NN   64
#define CC   256
#define SS   30
#define HWW  176
#define TOPK 10

// ---------------------------------------------------------------------------
// K0: build the exact spatial filter in fp64.
//   hh[0..511] : doubled fp32 table; hh[d] = h[d & 255].  h is the exact
//   irfft of the Gaussian mask (ortho norms fold to 1/256 overall):
//   h[d] = (1/256)[G(0) + (-1)^d G(128) + 2 sum_{m=1}^{127} G(m)cos(2pi d m/256)],
//   G(m)=exp(-0.5 (m/32)^2).  NOTE: h's tail only decays to ~1e-6 (Nyquist
//   kink in the mask) -> NO truncation is admissible (R2/R3 post-mortem).
// ---------------------------------------------------------------------------
__global__ void build_filter_kernel(float* __restrict__ hh) {
    const int d = threadIdx.x;           // 0..255
    const double theta = (2.0 * M_PI * (double)d) / 256.0;
    const double ct = cos(theta);
    double cm_prev = 1.0;
    double cm = ct;
    double acc = 0.0;
    for (int m = 1; m <= 127; ++m) {
        const double mm = (double)m / 32.0;
        const double G = exp(-0.5 * mm * mm);
        acc += G * cm;
        const double cn = 2.0 * ct * cm - cm_prev;
        cm_prev = cm;
        cm = cn;
    }
    const double G128 = exp(-8.0);
    double h = 1.0 + 2.0 * acc + ((d & 1) ? -G128 : G128);
    h /= 256.0;
    hh[d]       = (float)h;
    hh[d + 256] = (float)h;
}

// ---------------------------------------------------------------------------
// K1: FULL 256-tap circular conv along c + score.
// Block 256 thr = 4 waves, one (n, s, hw-tile-of-64).  X[256][64] staged in
// LDS (exactly 64 KB).  Wave w, chunk q computes c in [16w+64q, 16w+64q+16):
// 16 fp64 accumulators, 31-register sliding x-window (16 fresh uniform-row
// ds_reads per 256 v_fmac), taps h[16b..16b+15] via uniform s_loads.
// Accumulation: 16-term fp32 fma block-partials summed in fp64 (~3x lower
// noise than sequential fp32; R1's sequential fp32 passed at 0.0586).
// ---------------------------------------------------------------------------
__global__ __launch_bounds__(256)
void conv_score_kernel(const float* __restrict__ seqs,
                       const float* __restrict__ htab,   // hh (first 256 = h)
                       float* __restrict__ scores,
                       int n0) {
    __shared__ float Xd[CC][64];                         // 65536 B
    const int tid  = threadIdx.x;
    const int lane = tid & 63;
    const int wid  = tid >> 6;           // 0..3
    const int hwt  = blockIdx.x;         // 0..2
    const int s    = blockIdx.y;         // 0..29
    const int nrel = blockIdx.z;
    const int n    = n0 + nrel;
    const int hw0  = hwt * 64;
    const int hw   = hw0 + lane;
    const bool valid = (hw < HWW);
    const int  hwc   = valid ? hw : HWW - 1;             // clamp, never stored

    // ---- stage X[c][lane] = x[n, c, s, hw], coalesced; wave w does rows w+4k
    const size_t nbase = (size_t)n * CC * SS * HWW;
    for (int e = tid; e < CC * 64; e += 256) {
        const int row = e >> 6;
        Xd[row][e & 63] = seqs[nbase + ((size_t)row * SS + s) * HWW + hwc];
    }
    __syncthreads();

    #define XROW(r) Xd[(r) & (CC - 1)][lane]

    for (int q = 0; q < 4; ++q) {
        const int c0 = wid * 16 + q * 64;                // uniform per wave

        double acc[16];
        #pragma unroll
        for (int i = 0; i < 16; ++i) acc[i] = 0.0;

        float w[31];
        #pragma unroll
        for (int j = 0; j < 31; ++j) w[j] = XROW(c0 + 1 + j);

        float cen[16];

        #pragma unroll
        for (int t = 0; t < 16; ++t) {
            const int b = 15 - t;                        // tap block: u = 16b+j
            float hv[16];
            #pragma unroll
            for (int j = 0; j < 16; ++j) hv[j] = htab[16 * b + j];  // uniform

            // invariant: w[m] = x[(c0 + 1 + 16t + m) & 255]
            #pragma unroll
            for (int i = 0; i < 16; ++i) {
                float p = 0.0f;
                #pragma unroll
                for (int j = 0; j < 16; ++j)
                    p = fmaf(hv[j], w[15 + i - j], p);   // x[(c0+i-16b-j)&255]
                acc[i] += (double)p;
            }
            if (t == 15) {                               // u=0 tap row = center
                #pragma unroll
                for (int i = 0; i < 16; ++i) cen[i] = w[15 + i];
            } else {
                #pragma unroll
                for (int j = 0; j < 15; ++j) w[j] = w[j + 16];
                #pragma unroll
                for (int j = 15; j < 31; ++j) w[j] = XROW(c0 + 1 + 16 * (t + 1) + j);
            }
        }

        if (valid) {
            #pragma unroll
            for (int i = 0; i < 16; ++i) {
                const double low = acc[i];
                const float num = (float)fabs(low);
                const float den = (float)fabs(low - (double)cen[i]) + 1e-6f;
                scores[(((size_t)nrel * CC + (c0 + i)) * SS + s) * HWW + hw] =
                    num / den;
            }
        }
    }
    #undef XROW
}

// ---------------------------------------------------------------------------
// K2: per-(n,c,hw) thread.  30 score + 30 x coalesced loads; bitmask top-10
// (strict >, ascending s => lowest-index tie-break = lax.top_k), selected x
// tracked through the same cndmask chain; fused max-pool + sigmoid blend.
// ---------------------------------------------------------------------------
__device__ __forceinline__ float tmax30(const float* v) {
    float m[15];
    #pragma unroll
    for (int i = 0; i < 15; ++i) m[i] = fmaxf(v[i], v[i + 15]);
    #pragma unroll
    for (int i = 0; i < 7; ++i) m[i] = fmaxf(m[i], m[i + 8]);
    #pragma unroll
    for (int i = 0; i < 4; ++i) m[i] = fmaxf(m[i], m[i + 4]);
    m[0] = fmaxf(m[0], m[2]);
    m[1] = fmaxf(m[1], m[3]);
    return fmaxf(m[0], m[1]);
}

__global__ __launch_bounds__(256)
void topk_pool_kernel(const float* __restrict__ seqs,
                      const float* __restrict__ scores,
                      const float* __restrict__ logit_p,
                      float* __restrict__ out,
                      int n0) {
    const int tid  = threadIdx.x;
    const int lane = tid & 63;
    const int cq   = tid >> 6;                 // 0..3
    const int hwt  = blockIdx.x;               // 0..2
    const int cg   = blockIdx.y;               // 0..63
    const int nrel = blockIdx.z;
    const int n    = n0 + nrel;
    const int c    = cg * 4 + cq;
    const int hw   = hwt * 64 + lane;
    const bool valid = (hw < HWW);
    const int hwc  = valid ? hw : HWW - 1;

    const size_t bx = ((size_t)(n    * CC + c) * SS) * HWW + hwc;
    const size_t bk = ((size_t)(nrel * CC + c) * SS) * HWW + hwc;

    float xk[SS], kk[SS];
    #pragma unroll
    for (int s = 0; s < SS; ++s) xk[s] = seqs[bx + (size_t)s * HWW];
    #pragma unroll
    for (int s = 0; s < SS; ++s) kk[s] = scores[bk + (size_t)s * HWW];

    const float mx = tmax30(xk);

    unsigned taken = 0u;
    float sum = 0.0f;
    #pragma unroll 1
    for (int p = 0; p < TOPK; ++p) {
        float best = -1.0f;                    // scores >= 0
        float bxv  = 0.0f;
        unsigned bbit = 0u;
        #pragma unroll
        for (int s = 0; s < SS; ++s) {
            const bool ok = (((taken >> s) & 1u) == 0u) && (kk[s] > best);
            best = ok ? kk[s] : best;
            bxv  = ok ? xk[s] : bxv;
            bbit = ok ? (1u << s) : bbit;
        }
        taken |= bbit;
        sum += bxv;
    }

    const float alpha = 1.0f / (1.0f + expf(-logit_p[0]));
    if (valid)
        out[((size_t)n * CC + c) * HWW + hw] =
            alpha * (sum * 0.1f) + (1.0f - alpha) * mx;
}

// ---------------------------------------------------------------------------
// Fallback (round-1 kernel, known-correct): only if ws is too small.
// ---------------------------------------------------------------------------
__global__ __launch_bounds__(64, 3)
void fallback_pool_kernel(const float* __restrict__ seqs,
                          const float* __restrict__ logit_p,
                          const float* __restrict__ hh_g,
                          float* __restrict__ out) {
    __shared__ float hh[512];
    const int lane = threadIdx.x;
    const int hw = blockIdx.x % HWW;
    const int n  = blockIdx.x / HWW;
    for (int i = lane; i < 512; i += 64) hh[i] = hh_g[i];
    __syncthreads();

    float acc[4][SS];
    #pragma unroll
    for (int j = 0; j < 4; ++j)
        #pragma unroll
        for (int s = 0; s < SS; ++s) acc[j][s] = 0.0f;

    const size_t row_stride = (size_t)SS * HWW;
    const float* __restrict__ xbase = seqs + (size_t)n * CC * row_stride + hw;

    for (int k = 0; k < CC; ++k) {
        const float* __restrict__ xrow = xbase + (size_t)k * row_stride;
        const int hbase = lane + 256 - k;
        const float h0 = hh[hbase];
        const float h1 = hh[hbase + 64];
        const float h2 = hh[hbase + 128];
        const float h3 = hh[hbase + 192];
        #pragma unroll
        for (int s = 0; s < SS; ++s) {
            const float xv = xrow[(size_t)s * HWW];
            acc[0][s] = fmaf(xv, h0, acc[0][s]);
            acc[1][s] = fmaf(xv, h1, acc[1][s]);
            acc[2][s] = fmaf(xv, h2, acc[2][s]);
            acc[3][s] = fmaf(xv, h3, acc[3][s]);
        }
    }

    const float logit = logit_p[0];
    const float alpha = 1.0f / (1.0f + expf(-logit));
    const float beta  = 1.0f - alpha;

    #pragma unroll
    for (int j = 0; j < 4; ++j) {
        const int c = lane + 64 * j;
        const float* __restrict__ xr =
            seqs + ((size_t)(n * CC + c)) * row_stride + hw;
        float mmax = -INFINITY;
        #pragma unroll
        for (int s = 0; s < SS; ++s) {
            const float xv = xr[(size_t)s * HWW];
            const float lo = acc[j][s];
            acc[j][s] = fabsf(lo) / (fabsf(lo - xv) + 1e-6f);
            mmax = fmaxf(mmax, xv);
        }
        unsigned taken = 0u;
        float sum = 0.0f;
        #pragma unroll 1
        for (int t = 0; t < TOPK; ++t) {
            float best = -1.0f;
            int bi = 0;
            #pragma unroll
            for (int s = 0; s < SS; ++s) {
                const float v = acc[j][s];
                const bool ok = (((taken >> s) & 1u) == 0u) && (v > best);
                best = ok ? v : best;
                bi   = ok ? s : bi;
            }
            taken |= (1u << bi);
            sum += xr[(size_t)bi * HWW];
        }
        out[((size_t)(n * CC + c)) * HWW + hw] =
            alpha * (sum / 10.0f) + beta * mmax;
    }
}

// ---------------------------------------------------------------------------
extern "C" void kernel_launch(void* const* d_in, const int* in_sizes, int n_in,
                              void* d_out, int out_size, void* d_ws, size_t ws_size,
                              hipStream_t stream) {
    const float* seqs   = (const float*)d_in[0];
    const float* logitp = (const float*)d_in[1];
    float* outp = (float*)d_out;

    float* hh       = (float*)d_ws;                    // 512 fp32 (2 KB)
    float* scorebuf = (float*)((char*)d_ws + 4096);

    hipLaunchKernelGGL(build_filter_kernel, dim3(1), dim3(256), 0, stream, hh);

    const size_t bytes_per_n = (size_t)CC * SS * HWW * sizeof(float);  // 5.4 MB
    const size_t avail = (ws_size > 4096) ? (ws_size - 4096) : 0;
    int chunk = (int)(avail / bytes_per_n);
    if (chunk > NN) chunk = NN;

    if (chunk >= 1) {
        for (int na = 0; na < NN; na += chunk) {
            const int nc = (NN - na < chunk) ? (NN - na) : chunk;
            hipLaunchKernelGGL(conv_score_kernel, dim3(3, SS, nc), dim3(256), 0, stream,
                               seqs, hh, scorebuf, na);
            hipLaunchKernelGGL(topk_pool_kernel, dim3(3, 64, nc), dim3(256), 0, stream,
                               seqs, (const float*)scorebuf, logitp, outp, na);
        }
    } else {
        hipLaunchKernelGGL(fallback_pool_kernel, dim3(NN * HWW), dim3(64), 0, stream,
                           seqs, logitp, hh, outp);
    }
}